// Round 8
// baseline (782.205 us; speedup 1.0000x reference)
//
#include <hip/hip_runtime.h>
#include <hip/hip_bf16.h>

// MPNN on MI355X.
// Identities used:
//  (1) sum_e relu(a[dst]+b[src]) @ w2 == (sum_e relu(a[dst]+b[src])) @ w2
//  (2) (x@lin_w+lin_b)@w1 == x@(lin_w@w1) + (lin_b@w1)  -> lin GEMM composed into w1 GEMM
// Per layer: ONE 256-col GEMM (composed), XCD-sharded gather, ONE 128-col GEMM (w2).
// CSR build: fully deterministic counting sort -- NO global atomics on any per-edge path
// (R5: 800k returning global atomics = 66us; R6: contended bcnt atomics + 104-block tail =
// 77us). hist[blk][bkt] -> per-bucket scan over blocks -> rank scatter via LDS atomics only.
// Gather shards columns across XCDs (slice = blockIdx&7): per-XCD working set 3.2MB fits the
// 4MB per-XCD L2, turning random 256B reads (57% miss) into 32B L2 hits.

typedef _Float16 f16_t;
typedef f16_t f16x2 __attribute__((ext_vector_type(2)));
typedef f16_t f16x8 __attribute__((ext_vector_type(8)));
typedef float f32x4 __attribute__((ext_vector_type(4)));
typedef unsigned int u32;
typedef unsigned short u16;

__device__ __forceinline__ float f16lo(u32 v) {
    return (float)__builtin_bit_cast(f16_t, (u16)(v & 0xffff));
}
__device__ __forceinline__ float f16hi(u32 v) {
    return (float)__builtin_bit_cast(f16_t, (u16)(v >> 16));
}
__device__ __forceinline__ u32 f16pack(float x, float y) {
    u16 a = __builtin_bit_cast(u16, (f16_t)x);
    u16 b = __builtin_bit_cast(u16, (f16_t)y);
    return (u32)a | ((u32)b << 16);
}
__device__ __forceinline__ f16x2 relu_add2(f16x2 a, f16x2 b) {
    f16x2 s = a + b;                                // v_pk_add_f16
    return __builtin_elementwise_max(s, (f16x2)0);  // v_pk_max_f16
}
__device__ __forceinline__ f16x2 bcf(u32 v) { return __builtin_bit_cast(f16x2, v); }
__device__ __forceinline__ u32 bci(f16x2 v) { return __builtin_bit_cast(u32, v); }

// ---------------- fused prep: convx | prepw x3 | edge histogram ----------------
struct PrepArgs {
    const float* x; f16_t* xb; int totalx;
    const int* ei; int E;
    int* hist; int nbk; int NB;
    const float* lin_w[3]; const float* lin_b[3];
    const float* w1[3]; const float* b1[3]; const float* w2[3];
    f16_t* W12ct; f16_t* W2t; float* bias256c;  // per-layer strides 32768 / 16384 / 256
};

__global__ __launch_bounds__(256) void prep_kernel(PrepArgs A, int nConvB) {
    __shared__ int shm[512];
    const int b = blockIdx.x, tid = threadIdx.x;
    if (b < nConvB) {
        int i = (b * 256 + tid) * 4;
        if (i >= A.totalx) return;
        float4 v = *(const float4*)(A.x + i);
        *(uint2*)(A.xb + i) = make_uint2(f16pack(v.x, v.y), f16pack(v.z, v.w));
        return;
    }
    int pb = b - nConvB;
    if (pb < 3 * 193) {
        int layer = pb / 193;
        int idx = (pb % 193) * 256 + tid;
        const float* lin_w = A.lin_w[layer]; const float* lin_b = A.lin_b[layer];
        const float* w1 = A.w1[layer]; const float* b1 = A.b1[layer];
        const float* w2 = A.w2[layer];
        f16_t* W12ct = A.W12ct + layer * 32768;
        f16_t* W2t = A.W2t + layer * 16384;
        float* bias256c = A.bias256c + layer * 256;
        if (idx < 32768) {
            int j = idx >> 7, k = idx & 127;
            const float* wcol = (j < 128) ? (w1 + j) : (w1 + 128 * 128 + (j - 128));
            const float* lrow = lin_w + k * 128;
            float s = 0.f;
#pragma unroll 4
            for (int c = 0; c < 128; ++c) s += lrow[c] * wcol[c * 128];
            W12ct[idx] = (f16_t)s;
        } else if (idx < 32768 + 16384) {
            int i = idx - 32768;
            int j = i >> 7, k = i & 127;
            W2t[i] = (f16_t)w2[k * 128 + j];
        } else if (idx < 32768 + 16384 + 256) {
            int j = idx - 49152;
            const float* wcol = (j < 128) ? (w1 + j) : (w1 + 128 * 128 + (j - 128));
            float s = (j < 128) ? b1[j] : 0.f;
            for (int c = 0; c < 128; ++c) s += lin_b[c] * wcol[c * 128];
            bias256c[j] = s;
        }
        return;
    }
    // ---- edge histogram: bucket = dst>>7 (128 nodes/bucket), LDS counters only ----
    const int bb = pb - 3 * 193;
    const int nbk = A.nbk, E = A.E;
    for (int i = tid; i < nbk; i += 256) shm[i] = 0;
    __syncthreads();
    const int chunk = (E + A.NB - 1) / A.NB;
    const int e0 = bb * chunk, e1 = min(E, e0 + chunk);
    for (int e = e0 + tid; e < e1; e += 256) atomicAdd(&shm[A.ei[E + e] >> 7], 1);
    __syncthreads();
    for (int i = tid; i < nbk; i += 256) A.hist[(size_t)bb * nbk + i] = shm[i];
}

// ---------------- hscan: per-bucket exclusive scan of per-block counts ----------------
__global__ __launch_bounds__(256) void hscan_kernel(int* __restrict__ hist,
                                                    int* __restrict__ bcnt, int nbk, int NB) {
    __shared__ int sh[256];
    const int b = blockIdx.x, t = threadIdx.x;
    int run = 0;
    for (int c0 = 0; c0 < NB; c0 += 256) {
        int idx = c0 + t;
        int v = (idx < NB) ? hist[(size_t)idx * nbk + b] : 0;
        sh[t] = v;
        __syncthreads();
#pragma unroll
        for (int o = 1; o < 256; o <<= 1) {
            int u = (t >= o) ? sh[t - o] : 0;
            __syncthreads();
            sh[t] += u;
            __syncthreads();
        }
        if (idx < NB) hist[(size_t)idx * nbk + b] = run + sh[t] - v;
        int tot = sh[255];
        __syncthreads();
        run += tot;
    }
    if (t == 0) bcnt[b] = run;
}

// ---------------- scat: write packed (dst&127)<<16|src at precomputed base + LDS rank ------
__global__ __launch_bounds__(256) void scat_kernel(const int* __restrict__ ei,
                                                   const int* __restrict__ hist,
                                                   u32* __restrict__ bbuf, int E, int NB,
                                                   int nbk, int cap) {
    __shared__ int basep[512];
    __shared__ int cnt2[512];
    const int bb = blockIdx.x, t = threadIdx.x;
    for (int i = t; i < nbk; i += 256) {
        basep[i] = hist[(size_t)bb * nbk + i];  // contiguous read
        cnt2[i] = 0;
    }
    __syncthreads();
    const int chunk = (E + NB - 1) / NB;
    const int e0 = bb * chunk, e1 = min(E, e0 + chunk);
    for (int e = e0 + t; e < e1; e += 256) {
        int dst = ei[E + e], src = ei[e];
        int bkt = dst >> 7;
        int r = atomicAdd(&cnt2[bkt], 1);  // LDS returning atomic: cheap
        int pp = basep[bkt] + r;
        if (pp < cap) bbuf[(size_t)bkt * cap + pp] = ((u32)(dst & 127) << 16) | (u32)src;
    }
}

// ---------------- part2: per-bucket degree + local scan ----------------
__global__ __launch_bounds__(128) void part2_kernel(const u32* __restrict__ bbuf,
                                                    const int* __restrict__ bcnt,
                                                    int* __restrict__ row_ptr,
                                                    float* __restrict__ cntp1f,
                                                    int* __restrict__ bsumB, int cap, int N) {
    __shared__ int ldeg[128];
    __shared__ int sh[128];
    const int b = blockIdx.x, t = threadIdx.x;
    ldeg[t] = 0;
    __syncthreads();
    const int cnt = min(bcnt[b], cap);
    const u32* p = bbuf + (size_t)b * cap;
    for (int i = t; i < cnt; i += 128) atomicAdd(&ldeg[p[i] >> 16], 1);
    __syncthreads();
    int d = ldeg[t];
    sh[t] = d;
    __syncthreads();
#pragma unroll
    for (int o = 1; o < 128; o <<= 1) {
        int u = (t >= o) ? sh[t - o] : 0;
        __syncthreads();
        sh[t] += u;
        __syncthreads();
    }
    int node = (b << 7) + t;
    if (node < N) {
        row_ptr[node] = sh[t] - d;  // bucket-local prefix; part3 adds bucket base
        cntp1f[node] = (float)(d + 1);
    }
    if (t == 127) bsumB[b] = sh[127];
}

// ---------------- scanB: exclusive scan of bucket totals (1 block) ----------------
__global__ __launch_bounds__(512) void scanb_kernel(const int* __restrict__ bsumB,
                                                    int* __restrict__ bbase,
                                                    int* __restrict__ row_ptr, int nbk, int N) {
    __shared__ int sh[512];
    const int t = threadIdx.x;
    int v = (t < nbk) ? bsumB[t] : 0;
    sh[t] = v;
    __syncthreads();
#pragma unroll
    for (int o = 1; o < 512; o <<= 1) {
        int u = (t >= o) ? sh[t - o] : 0;
        __syncthreads();
        sh[t] += u;
        __syncthreads();
    }
    if (t < nbk) bbase[t] = sh[t] - v;
    if (t == 511) row_ptr[N] = sh[511];
}

// ---------------- part3: finalize row_ptr, scatter colarr within bucket window -------------
__global__ __launch_bounds__(128) void part3_kernel(const u32* __restrict__ bbuf,
                                                    const int* __restrict__ bcnt,
                                                    const int* __restrict__ bbase,
                                                    int* __restrict__ row_ptr,
                                                    int* __restrict__ colarr, int cap, int N) {
    __shared__ int lcur[128];
    const int b = blockIdx.x, t = threadIdx.x;
    const int node = (b << 7) + t;
    const int bb = bbase[b];
    int rp = 0;
    if (node < N) {
        rp = row_ptr[node] + bb;
        row_ptr[node] = rp;  // final global row_ptr
    }
    lcur[t] = rp;
    __syncthreads();
    const int cnt = min(bcnt[b], cap);
    const u32* p = bbuf + (size_t)b * cap;
    for (int i = t; i < cnt; i += 128) {
        u32 en = p[i];
        int addr = atomicAdd(&lcur[en >> 16], 1);  // LDS returning atomic
        colarr[addr] = (int)(en & 0xffffu);
    }
}

// ---------------- node GEMM: Y[N, ldc] = X[N,128] @ Wt^T + epilogue (MFMA fp16) ------------
__global__ __launch_bounds__(256) void gemm_node(const f16_t* __restrict__ X,
                                                 const f16_t* __restrict__ Wt,
                                                 const float* __restrict__ bias,
                                                 const float* __restrict__ bias2,
                                                 const float* __restrict__ rowscale,
                                                 f16_t* __restrict__ Y, int N, int ldc,
                                                 int relu_flag) {
    const int coloff = blockIdx.y * 128;
    __shared__ f16_t sX[128 * 128];
    __shared__ f16_t sW[128 * 128];
    const int tid = threadIdx.x;
    const int row0 = blockIdx.x * 128;
#pragma unroll
    for (int it = 0; it < 8; ++it) {
        int idx = tid + it * 256;
        int r = idx >> 4, c8 = idx & 15;
        int gr = row0 + r;
        uint4 v = make_uint4(0, 0, 0, 0);
        if (gr < N) v = *(const uint4*)(X + (size_t)gr * 128 + c8 * 8);
        *(uint4*)(&sX[r * 128 + (c8 ^ (r & 7)) * 8]) = v;
    }
#pragma unroll
    for (int it = 0; it < 8; ++it) {
        int idx = tid + it * 256;
        int r = idx >> 4, c8 = idx & 15;
        uint4 v = *(const uint4*)(Wt + (size_t)(coloff + r) * 128 + c8 * 8);
        *(uint4*)(&sW[r * 128 + (c8 ^ (r & 7)) * 8]) = v;
    }
    __syncthreads();
    const int wave = tid >> 6, lane = tid & 63;
    const int m = lane & 15, q = lane >> 4;
    const int sw = m & 7;
    f32x4 acc[2][8];
#pragma unroll
    for (int rt = 0; rt < 2; ++rt)
#pragma unroll
        for (int t = 0; t < 8; ++t) acc[rt][t] = (f32x4){0.f, 0.f, 0.f, 0.f};
#pragma unroll
    for (int kk = 0; kk < 4; ++kk) {
        const int g = (kk * 4 + q) ^ sw;
        f16x8 a0 = *(const f16x8*)(&sX[(wave * 32 + m) * 128 + g * 8]);
        f16x8 a1 = *(const f16x8*)(&sX[(wave * 32 + 16 + m) * 128 + g * 8]);
#pragma unroll
        for (int t = 0; t < 8; ++t) {
            f16x8 bfr = *(const f16x8*)(&sW[(t * 16 + m) * 128 + g * 8]);
            acc[0][t] = __builtin_amdgcn_mfma_f32_16x16x32_f16(a0, bfr, acc[0][t], 0, 0, 0);
            acc[1][t] = __builtin_amdgcn_mfma_f32_16x16x32_f16(a1, bfr, acc[1][t], 0, 0, 0);
        }
    }
#pragma unroll
    for (int t = 0; t < 8; ++t) {
        int col = coloff + t * 16 + m;
        float bv = bias ? bias[col] : 0.f;
        float b2v = bias2 ? bias2[col] : 0.f;
#pragma unroll
        for (int rt = 0; rt < 2; ++rt) {
#pragma unroll
            for (int j = 0; j < 4; ++j) {
                int r = row0 + wave * 32 + rt * 16 + q * 4 + j;
                if (r < N) {
                    float v = acc[rt][t][j] + bv;
                    if (rowscale) v += rowscale[r] * b2v;
                    if (relu_flag) v = fmaxf(v, 0.f);
                    Y[(size_t)r * ldc + col] = (f16_t)v;
                }
            }
        }
    }
}

// ---------------- gather, XCD-sharded by column slice ----------------
// slice = blockIdx&7 (round-robin XCD heuristic). Each slice covers 16 cols = 8 u32.
// Per-XCD working set: a-slice 1.6MB + b-slice 1.6MB -> fits 4MB per-XCD L2.
// Wave: 8 slots (edges in flight) x 8 lanes (u32 each). Reduce over slots via shfl_xor.
__global__ __launch_bounds__(256) void gather_kernel(const u32* __restrict__ abu,
                                                     const int* __restrict__ row_ptr,
                                                     const int* __restrict__ colarr,
                                                     u32* __restrict__ q, int N, int B2) {
    const int slice = blockIdx.x & 7;
    const int tid = threadIdx.x, lane = tid & 63, wave = tid >> 6;
    const int slot = lane >> 3, li = lane & 7;
    const int off = slice * 8 + li;  // u32 col for a; +64 for b
    int w = (int)(blockIdx.x >> 3) * 4 + wave;
    const int ws = B2 * 4;
    for (int n = w; n < N; n += ws) {
        const size_t rb = (size_t)n << 7;
        f16x2 av = bcf(abu[rb + off]);
        f16x2 c = (f16x2)0;
        if (slot == 0) c = relu_add2(av, bcf(abu[rb + 64 + off]));  // self loop
        int e0 = row_ptr[n], e1 = row_ptr[n + 1];
        int e = e0;
        for (; e + 16 <= e1; e += 16) {
            int s0 = colarr[e + slot], s1 = colarr[e + 8 + slot];
            u32 b0 = abu[((size_t)s0 << 7) + 64 + off];
            u32 b1 = abu[((size_t)s1 << 7) + 64 + off];
            c += relu_add2(av, bcf(b0));
            c += relu_add2(av, bcf(b1));
        }
        if (e + 8 <= e1) {
            int s0 = colarr[e + slot];
            c += relu_add2(av, bcf(abu[((size_t)s0 << 7) + 64 + off]));
            e += 8;
        }
        if (e + slot < e1) {
            int s0 = colarr[e + slot];
            c += relu_add2(av, bcf(abu[((size_t)s0 << 7) + 64 + off]));
        }
#pragma unroll
        for (int o = 8; o < 64; o <<= 1) c += bcf(__shfl_xor(bci(c), o));
        if (slot == 0) q[((size_t)n << 6) + off] = bci(c);
    }
}

// ---------------- pooling ----------------
__global__ __launch_bounds__(256) void pool_kernel(const f16_t* __restrict__ agg,
                                                   const int* __restrict__ batch,
                                                   float* __restrict__ pooled,
                                                   int* __restrict__ cntg, int N) {
    int wid = (blockIdx.x * 256 + threadIdx.x) >> 6;
    int lane = threadIdx.x & 63;
    int n0 = wid * 32;
    if (n0 >= N) return;
    int n1 = min(n0 + 32, N);
    const u32* au = (const u32*)agg;
    int gcur = batch[n0];
    float sx = 0.f, sy = 0.f;
    int cnt = 0;
    for (int n = n0; n < n1; ++n) {
        int g = batch[n];
        if (g != gcur) {
            atomicAdd(&pooled[gcur * 128 + lane * 2], sx);
            atomicAdd(&pooled[gcur * 128 + lane * 2 + 1], sy);
            if (lane == 0) atomicAdd(&cntg[gcur], cnt);
            gcur = g; sx = 0.f; sy = 0.f; cnt = 0;
        }
        u32 v = au[(size_t)n * 64 + lane];
        sx += f16lo(v);
        sy += f16hi(v);
        ++cnt;
    }
    atomicAdd(&pooled[gcur * 128 + lane * 2], sx);
    atomicAdd(&pooled[gcur * 128 + lane * 2 + 1], sy);
    if (lane == 0) atomicAdd(&cntg[gcur], cnt);
}

// ---------------- final ----------------
__global__ __launch_bounds__(256) void final_kernel(const float* __restrict__ pooled,
                                                    const int* __restrict__ cntg,
                                                    const float* __restrict__ out_w,
                                                    const float* __restrict__ out_b,
                                                    float* __restrict__ out, int total) {
    int idx = blockIdx.x * 256 + threadIdx.x;
    if (idx >= total) return;
    int g = idx >> 6, o = idx & 63;
    float c = fmaxf((float)cntg[g], 1.0f);
    float s = 0.f;
#pragma unroll 4
    for (int k = 0; k < 128; ++k) s += pooled[g * 128 + k] * out_w[k * 64 + o];
    out[idx] = s / c + out_b[o];
}

extern "C" void kernel_launch(void* const* d_in, const int* in_sizes, int n_in, void* d_out,
                              int out_size, void* d_ws, size_t ws_size, hipStream_t stream) {
    const float* x = (const float*)d_in[0];
    const int* ei = (const int*)d_in[1];
    const int* batch = (const int*)d_in[3];
    const float* cw[3][6];  // lin_w, lin_b, w1, b1, w2, b2
    for (int l = 0; l < 3; ++l)
        for (int j = 0; j < 6; ++j) cw[l][j] = (const float*)d_in[4 + l * 6 + j];
    const float* out_w = (const float*)d_in[22];
    const float* out_b = (const float*)d_in[23];
    float* out = (float*)d_out;

    const int N = in_sizes[0] / 128;
    const int E = in_sizes[1] / 2;
    const int G = out_size / 64;
    const int nbk = (N + 127) >> 7;       // buckets of 128 nodes (<=512 required)
    const int NB = 416;                   // edge-chunk blocks for hist/scat
    const int cap = E / nbk + 512;        // per-bucket capacity (mean + ~11 sigma)

    // ---- workspace layout ----
    char* base = (char*)d_ws;
    size_t off = 0;
    auto alloc = [&](size_t b) { size_t o = off; off += (b + 255) & ~(size_t)255; return o; };
    float* pooled = (float*)(base + alloc((size_t)G * 128 * 4));
    int* cntg = (int*)(base + alloc((size_t)G * 4));
    const size_t zero_bytes = off;
    int* hist = (int*)(base + alloc((size_t)NB * nbk * 4));
    int* bcnt = (int*)(base + alloc((size_t)nbk * 4));
    int* bsumB = (int*)(base + alloc((size_t)nbk * 4));
    int* bbase = (int*)(base + alloc((size_t)nbk * 4));
    int* row_ptr = (int*)(base + alloc((size_t)(N + 1) * 4));
    float* cntp1f = (float*)(base + alloc((size_t)N * 4));
    int* colarr = (int*)(base + alloc((size_t)E * 4));
    u32* bbuf = (u32*)(base + alloc((size_t)nbk * cap * 4));
    f16_t* xb = (f16_t*)(base + alloc((size_t)N * 128 * 2));  // layer input / agg output
    f16_t* q = (f16_t*)(base + alloc((size_t)N * 128 * 2));   // gather output
    f16_t* ab = (f16_t*)(base + alloc((size_t)N * 256 * 2));  // [a|b]
    f16_t* W12ct = (f16_t*)(base + alloc(3 * 32768 * 2));
    f16_t* W2t = (f16_t*)(base + alloc(3 * 16384 * 2));
    float* bias256c = (float*)(base + alloc(3 * 256 * 4));
    (void)ws_size; (void)n_in;

    hipMemsetAsync(d_ws, 0, zero_bytes, stream);

    // fused prep: convx | prepw x3 | histogram
    PrepArgs pa;
    pa.x = x; pa.xb = xb; pa.totalx = N * 128;
    pa.ei = ei; pa.E = E;
    pa.hist = hist; pa.nbk = nbk; pa.NB = NB;
    for (int l = 0; l < 3; ++l) {
        pa.lin_w[l] = cw[l][0]; pa.lin_b[l] = cw[l][1];
        pa.w1[l] = cw[l][2]; pa.b1[l] = cw[l][3]; pa.w2[l] = cw[l][4];
    }
    pa.W12ct = W12ct; pa.W2t = W2t; pa.bias256c = bias256c;
    const int nConvB = (N * 128 / 4 + 255) / 256;
    prep_kernel<<<nConvB + 3 * 193 + NB, 256, 0, stream>>>(pa, nConvB);

    // CSR: deterministic counting sort (no global atomics)
    hscan_kernel<<<nbk, 256, 0, stream>>>(hist, bcnt, nbk, NB);
    scat_kernel<<<NB, 256, 0, stream>>>(ei, hist, bbuf, E, NB, nbk, cap);
    part2_kernel<<<nbk, 128, 0, stream>>>(bbuf, bcnt, row_ptr, cntp1f, bsumB, cap, N);
    scanb_kernel<<<1, 512, 0, stream>>>(bsumB, bbase, row_ptr, nbk, N);
    part3_kernel<<<nbk, 128, 0, stream>>>(bbuf, bcnt, bbase, row_ptr, colarr, cap, N);

    const int gblocks = (N + 127) / 128;
    auto gemm = [&](const f16_t* X, const f16_t* Wt, const float* bias, const float* bias2,
                    const float* rowscale, f16_t* Y, int ncol, int relu_flag) {
        gemm_node<<<dim3(gblocks, ncol / 128), 256, 0, stream>>>(X, Wt, bias, bias2, rowscale, Y,
                                                                 N, ncol, relu_flag);
    };

    const int B2 = 640;  // gather blocks per slice; grid = 8*B2
    const f16_t* Xin = xb;
    for (int l = 0; l < 3; ++l) {
        gemm(Xin, W12ct + l * 32768, bias256c + l * 256, nullptr, nullptr, ab, 256, 0);
        gather_kernel<<<8 * B2, 256, 0, stream>>>((const u32*)ab, row_ptr, colarr, (u32*)q, N,
                                                  B2);
        gemm(q, W2t + l * 16384, nullptr, cw[l][5], cntp1f, xb, 128, 1);
        Xin = xb;
    }

    pool_kernel<<<((N + 31) / 32 * 64 + 255) / 256, 256, 0, stream>>>(Xin, batch, pooled, cntg, N);
    final_kernel<<<(G * 64 + 255) / 256, 256, 0, stream>>>(pooled, cntg, out_w, out_b, out,
                                                           G * 64);
}

// Round 9
// 500.018 us; speedup vs baseline: 1.5644x; 1.5644x over previous
//
#include <hip/hip_runtime.h>
#include <hip/hip_bf16.h>

// MPNN on MI355X.
// Identities used:
//  (1) sum_e relu(a[dst]+b[src]) @ w2 == (sum_e relu(a[dst]+b[src])) @ w2
//  (2) (x@lin_w+lin_b)@w1 == x@(lin_w@w1) + (lin_b@w1)  -> lin GEMM composed into w1 GEMM
// Per layer: ONE 256-col GEMM (composed), gather(edge add+relu+acc), ONE 128-col GEMM (w2).
// Intermediates FP16 (packed v_pk_add/max_f16).
// CSR build: deterministic counting sort (hist -> per-bucket scan -> rank scatter, LDS
// atomics only). colarr is u16 (N < 65536).
// R8 lesson: do NOT shard gather columns across XCDs -- sub-line reads of the same row from
// different XCDs re-fetch whole lines per XCD (FETCH 88->241MB, 3x regression). Gather reads
// the full 256B b-row per edge from one wave.

typedef _Float16 f16_t;
typedef f16_t f16x2 __attribute__((ext_vector_type(2)));
typedef f16_t f16x8 __attribute__((ext_vector_type(8)));
typedef float f32x4 __attribute__((ext_vector_type(4)));
typedef unsigned int u32;
typedef unsigned short u16;

__device__ __forceinline__ float f16lo(u32 v) {
    return (float)__builtin_bit_cast(f16_t, (u16)(v & 0xffff));
}
__device__ __forceinline__ float f16hi(u32 v) {
    return (float)__builtin_bit_cast(f16_t, (u16)(v >> 16));
}
__device__ __forceinline__ u32 f16pack(float x, float y) {
    u16 a = __builtin_bit_cast(u16, (f16_t)x);
    u16 b = __builtin_bit_cast(u16, (f16_t)y);
    return (u32)a | ((u32)b << 16);
}
__device__ __forceinline__ f16x2 relu_add2(f16x2 a, f16x2 b) {
    f16x2 s = a + b;                                // v_pk_add_f16
    return __builtin_elementwise_max(s, (f16x2)0);  // v_pk_max_f16
}
__device__ __forceinline__ f16x2 bcf(u32 v) { return __builtin_bit_cast(f16x2, v); }
__device__ __forceinline__ u32 bci(f16x2 v) { return __builtin_bit_cast(u32, v); }

// ---------------- fused prep: convx | prepw x3 | edge histogram ----------------
struct PrepArgs {
    const float* x; f16_t* xb; int totalx;
    const int* ei; int E;
    int* hist; int nbk; int NB;
    const float* lin_w[3]; const float* lin_b[3];
    const float* w1[3]; const float* b1[3]; const float* w2[3];
    f16_t* W12ct; f16_t* W2t; float* bias256c;  // per-layer strides 32768 / 16384 / 256
};

__global__ __launch_bounds__(256) void prep_kernel(PrepArgs A, int nConvB) {
    __shared__ int shm[512];
    const int b = blockIdx.x, tid = threadIdx.x;
    if (b < nConvB) {
        int i = (b * 256 + tid) * 4;
        if (i >= A.totalx) return;
        float4 v = *(const float4*)(A.x + i);
        *(uint2*)(A.xb + i) = make_uint2(f16pack(v.x, v.y), f16pack(v.z, v.w));
        return;
    }
    int pb = b - nConvB;
    if (pb < 3 * 193) {
        int layer = pb / 193;
        int idx = (pb % 193) * 256 + tid;
        const float* lin_w = A.lin_w[layer]; const float* lin_b = A.lin_b[layer];
        const float* w1 = A.w1[layer]; const float* b1 = A.b1[layer];
        const float* w2 = A.w2[layer];
        f16_t* W12ct = A.W12ct + layer * 32768;
        f16_t* W2t = A.W2t + layer * 16384;
        float* bias256c = A.bias256c + layer * 256;
        if (idx < 32768) {
            int j = idx >> 7, k = idx & 127;
            const float* wcol = (j < 128) ? (w1 + j) : (w1 + 128 * 128 + (j - 128));
            const float* lrow = lin_w + k * 128;
            float s = 0.f;
#pragma unroll 4
            for (int c = 0; c < 128; ++c) s += lrow[c] * wcol[c * 128];
            W12ct[idx] = (f16_t)s;
        } else if (idx < 32768 + 16384) {
            int i = idx - 32768;
            int j = i >> 7, k = i & 127;
            W2t[i] = (f16_t)w2[k * 128 + j];
        } else if (idx < 32768 + 16384 + 256) {
            int j = idx - 49152;
            const float* wcol = (j < 128) ? (w1 + j) : (w1 + 128 * 128 + (j - 128));
            float s = (j < 128) ? b1[j] : 0.f;
            for (int c = 0; c < 128; ++c) s += lin_b[c] * wcol[c * 128];
            bias256c[j] = s;
        }
        return;
    }
    // ---- edge histogram: bucket = dst>>7 (128 nodes/bucket), LDS counters only ----
    const int bb = pb - 3 * 193;
    const int nbk = A.nbk, E = A.E;
    for (int i = tid; i < nbk; i += 256) shm[i] = 0;
    __syncthreads();
    const int chunk = (E + A.NB - 1) / A.NB;
    const int e0 = bb * chunk, e1 = min(E, e0 + chunk);
    for (int e = e0 + tid; e < e1; e += 256) atomicAdd(&shm[A.ei[E + e] >> 7], 1);
    __syncthreads();
    for (int i = tid; i < nbk; i += 256) A.hist[(size_t)bb * nbk + i] = shm[i];
}

// ---------------- hscan: per-bucket exclusive scan of per-block counts ----------------
__global__ __launch_bounds__(256) void hscan_kernel(int* __restrict__ hist,
                                                    int* __restrict__ bcnt, int nbk, int NB) {
    __shared__ int sh[256];
    const int b = blockIdx.x, t = threadIdx.x;
    int run = 0;
    for (int c0 = 0; c0 < NB; c0 += 256) {
        int idx = c0 + t;
        int v = (idx < NB) ? hist[(size_t)idx * nbk + b] : 0;
        sh[t] = v;
        __syncthreads();
#pragma unroll
        for (int o = 1; o < 256; o <<= 1) {
            int u = (t >= o) ? sh[t - o] : 0;
            __syncthreads();
            sh[t] += u;
            __syncthreads();
        }
        if (idx < NB) hist[(size_t)idx * nbk + b] = run + sh[t] - v;
        int tot = sh[255];
        __syncthreads();
        run += tot;
    }
    if (t == 0) bcnt[b] = run;
}

// ---------------- scat: write packed (dst&127)<<16|src at precomputed base + LDS rank ------
__global__ __launch_bounds__(256) void scat_kernel(const int* __restrict__ ei,
                                                   const int* __restrict__ hist,
                                                   u32* __restrict__ bbuf, int E, int NB,
                                                   int nbk, int cap) {
    __shared__ int basep[512];
    __shared__ int cnt2[512];
    const int bb = blockIdx.x, t = threadIdx.x;
    for (int i = t; i < nbk; i += 256) {
        basep[i] = hist[(size_t)bb * nbk + i];  // contiguous read
        cnt2[i] = 0;
    }
    __syncthreads();
    const int chunk = (E + NB - 1) / NB;
    const int e0 = bb * chunk, e1 = min(E, e0 + chunk);
    for (int e = e0 + t; e < e1; e += 256) {
        int dst = ei[E + e], src = ei[e];
        int bkt = dst >> 7;
        int r = atomicAdd(&cnt2[bkt], 1);  // LDS returning atomic: cheap
        int pp = basep[bkt] + r;
        if (pp < cap) bbuf[(size_t)bkt * cap + pp] = ((u32)(dst & 127) << 16) | (u32)src;
    }
}

// ---------------- part2: per-bucket degree + local scan ----------------
__global__ __launch_bounds__(128) void part2_kernel(const u32* __restrict__ bbuf,
                                                    const int* __restrict__ bcnt,
                                                    int* __restrict__ row_ptr,
                                                    float* __restrict__ cntp1f,
                                                    int* __restrict__ bsumB, int cap, int N) {
    __shared__ int ldeg[128];
    __shared__ int sh[128];
    const int b = blockIdx.x, t = threadIdx.x;
    ldeg[t] = 0;
    __syncthreads();
    const int cnt = min(bcnt[b], cap);
    const u32* p = bbuf + (size_t)b * cap;
    for (int i = t; i < cnt; i += 128) atomicAdd(&ldeg[p[i] >> 16], 1);
    __syncthreads();
    int d = ldeg[t];
    sh[t] = d;
    __syncthreads();
#pragma unroll
    for (int o = 1; o < 128; o <<= 1) {
        int u = (t >= o) ? sh[t - o] : 0;
        __syncthreads();
        sh[t] += u;
        __syncthreads();
    }
    int node = (b << 7) + t;
    if (node < N) {
        row_ptr[node] = sh[t] - d;  // bucket-local prefix; part3 adds bucket base
        cntp1f[node] = (float)(d + 1);
    }
    if (t == 127) bsumB[b] = sh[127];
}

// ---------------- scanB: exclusive scan of bucket totals (1 block) ----------------
__global__ __launch_bounds__(512) void scanb_kernel(const int* __restrict__ bsumB,
                                                    int* __restrict__ bbase,
                                                    int* __restrict__ row_ptr, int nbk, int N) {
    __shared__ int sh[512];
    const int t = threadIdx.x;
    int v = (t < nbk) ? bsumB[t] : 0;
    sh[t] = v;
    __syncthreads();
#pragma unroll
    for (int o = 1; o < 512; o <<= 1) {
        int u = (t >= o) ? sh[t - o] : 0;
        __syncthreads();
        sh[t] += u;
        __syncthreads();
    }
    if (t < nbk) bbase[t] = sh[t] - v;
    if (t == 511) row_ptr[N] = sh[511];
}

// ---------------- part3: finalize row_ptr, scatter u16 colarr within bucket window ---------
__global__ __launch_bounds__(128) void part3_kernel(const u32* __restrict__ bbuf,
                                                    const int* __restrict__ bcnt,
                                                    const int* __restrict__ bbase,
                                                    int* __restrict__ row_ptr,
                                                    u16* __restrict__ colarr, int cap, int N) {
    __shared__ int lcur[128];
    const int b = blockIdx.x, t = threadIdx.x;
    const int node = (b << 7) + t;
    const int bb = bbase[b];
    int rp = 0;
    if (node < N) {
        rp = row_ptr[node] + bb;
        row_ptr[node] = rp;  // final global row_ptr
    }
    lcur[t] = rp;
    __syncthreads();
    const int cnt = min(bcnt[b], cap);
    const u32* p = bbuf + (size_t)b * cap;
    for (int i = t; i < cnt; i += 128) {
        u32 en = p[i];
        int addr = atomicAdd(&lcur[en >> 16], 1);  // LDS returning atomic
        colarr[addr] = (u16)(en & 0xffffu);
    }
}

// ---------------- node GEMM: Y[N, ldc] = X[N,128] @ Wt^T + epilogue (MFMA fp16) ------------
__global__ __launch_bounds__(256) void gemm_node(const f16_t* __restrict__ X,
                                                 const f16_t* __restrict__ Wt,
                                                 const float* __restrict__ bias,
                                                 const float* __restrict__ bias2,
                                                 const float* __restrict__ rowscale,
                                                 f16_t* __restrict__ Y, int N, int ldc,
                                                 int relu_flag) {
    const int coloff = blockIdx.y * 128;
    __shared__ f16_t sX[128 * 128];
    __shared__ f16_t sW[128 * 128];
    const int tid = threadIdx.x;
    const int row0 = blockIdx.x * 128;
#pragma unroll
    for (int it = 0; it < 8; ++it) {
        int idx = tid + it * 256;
        int r = idx >> 4, c8 = idx & 15;
        int gr = row0 + r;
        uint4 v = make_uint4(0, 0, 0, 0);
        if (gr < N) v = *(const uint4*)(X + (size_t)gr * 128 + c8 * 8);
        *(uint4*)(&sX[r * 128 + (c8 ^ (r & 7)) * 8]) = v;
    }
#pragma unroll
    for (int it = 0; it < 8; ++it) {
        int idx = tid + it * 256;
        int r = idx >> 4, c8 = idx & 15;
        uint4 v = *(const uint4*)(Wt + (size_t)(coloff + r) * 128 + c8 * 8);
        *(uint4*)(&sW[r * 128 + (c8 ^ (r & 7)) * 8]) = v;
    }
    __syncthreads();
    const int wave = tid >> 6, lane = tid & 63;
    const int m = lane & 15, q = lane >> 4;
    const int sw = m & 7;
    f32x4 acc[2][8];
#pragma unroll
    for (int rt = 0; rt < 2; ++rt)
#pragma unroll
        for (int t = 0; t < 8; ++t) acc[rt][t] = (f32x4){0.f, 0.f, 0.f, 0.f};
#pragma unroll
    for (int kk = 0; kk < 4; ++kk) {
        const int g = (kk * 4 + q) ^ sw;
        f16x8 a0 = *(const f16x8*)(&sX[(wave * 32 + m) * 128 + g * 8]);
        f16x8 a1 = *(const f16x8*)(&sX[(wave * 32 + 16 + m) * 128 + g * 8]);
#pragma unroll
        for (int t = 0; t < 8; ++t) {
            f16x8 bfr = *(const f16x8*)(&sW[(t * 16 + m) * 128 + g * 8]);
            acc[0][t] = __builtin_amdgcn_mfma_f32_16x16x32_f16(a0, bfr, acc[0][t], 0, 0, 0);
            acc[1][t] = __builtin_amdgcn_mfma_f32_16x16x32_f16(a1, bfr, acc[1][t], 0, 0, 0);
        }
    }
#pragma unroll
    for (int t = 0; t < 8; ++t) {
        int col = coloff + t * 16 + m;
        float bv = bias ? bias[col] : 0.f;
        float b2v = bias2 ? bias2[col] : 0.f;
#pragma unroll
        for (int rt = 0; rt < 2; ++rt) {
#pragma unroll
            for (int j = 0; j < 4; ++j) {
                int r = row0 + wave * 32 + rt * 16 + q * 4 + j;
                if (r < N) {
                    float v = acc[rt][t][j] + bv;
                    if (rowscale) v += rowscale[r] * b2v;
                    if (relu_flag) v = fmaxf(v, 0.f);
                    Y[(size_t)r * ldc + col] = (f16_t)v;
                }
            }
        }
    }
}

// ---------------- edge aggregation: packed fp16, 16 edges in flight per wave ----------------
// ab: [N,256] f16 = [N,32] uint4; a = uint4 0..15, b = uint4 16..31 of each row.
// Wave per node; lane group g=lane>>4 covers 4 edge slots; lane-in-group l covers 8 cols.
__global__ __launch_bounds__(256) void gather_kernel(const f16_t* __restrict__ ab,
                                                     const int* __restrict__ row_ptr,
                                                     const u16* __restrict__ colarr,
                                                     f16_t* __restrict__ q, int N) {
    int wid = (blockIdx.x * 256 + threadIdx.x) >> 6;
    int lane = threadIdx.x & 63;
    if (wid >= N) return;
    const uint4* abu4 = (const uint4*)ab;
    const int g = lane >> 4, l = lane & 15;
    uint4 A = abu4[(size_t)wid * 32 + l];
    f16x2 a0 = bcf(A.x), a1 = bcf(A.y), a2 = bcf(A.z), a3 = bcf(A.w);
    f16x2 c0 = (f16x2)0, c1 = (f16x2)0, c2 = (f16x2)0, c3 = (f16x2)0;
    if (g == 0) {  // self loop, counted once
        uint4 B = abu4[(size_t)wid * 32 + 16 + l];
        c0 = relu_add2(a0, bcf(B.x));
        c1 = relu_add2(a1, bcf(B.y));
        c2 = relu_add2(a2, bcf(B.z));
        c3 = relu_add2(a3, bcf(B.w));
    }
    int e0 = row_ptr[wid], e1 = row_ptr[wid + 1];
    int e = e0;
    for (; e + 16 <= e1; e += 16) {
        int s0 = colarr[e + g], s1 = colarr[e + 4 + g];
        int s2 = colarr[e + 8 + g], s3 = colarr[e + 12 + g];
        uint4 B0 = abu4[(size_t)s0 * 32 + 16 + l];
        uint4 B1 = abu4[(size_t)s1 * 32 + 16 + l];
        uint4 B2 = abu4[(size_t)s2 * 32 + 16 + l];
        uint4 B3 = abu4[(size_t)s3 * 32 + 16 + l];
        c0 += relu_add2(a0, bcf(B0.x)); c1 += relu_add2(a1, bcf(B0.y));
        c2 += relu_add2(a2, bcf(B0.z)); c3 += relu_add2(a3, bcf(B0.w));
        c0 += relu_add2(a0, bcf(B1.x)); c1 += relu_add2(a1, bcf(B1.y));
        c2 += relu_add2(a2, bcf(B1.z)); c3 += relu_add2(a3, bcf(B1.w));
        c0 += relu_add2(a0, bcf(B2.x)); c1 += relu_add2(a1, bcf(B2.y));
        c2 += relu_add2(a2, bcf(B2.z)); c3 += relu_add2(a3, bcf(B2.w));
        c0 += relu_add2(a0, bcf(B3.x)); c1 += relu_add2(a1, bcf(B3.y));
        c2 += relu_add2(a2, bcf(B3.z)); c3 += relu_add2(a3, bcf(B3.w));
    }
    for (; e < e1; e += 4) {
        int i0 = e + g;
        if (i0 < e1) {
            int src = colarr[i0];
            uint4 B = abu4[(size_t)src * 32 + 16 + l];
            c0 += relu_add2(a0, bcf(B.x)); c1 += relu_add2(a1, bcf(B.y));
            c2 += relu_add2(a2, bcf(B.z)); c3 += relu_add2(a3, bcf(B.w));
        }
    }
#pragma unroll
    for (int off = 16; off < 64; off <<= 1) {
        c0 += bcf(__shfl_xor(bci(c0), off));
        c1 += bcf(__shfl_xor(bci(c1), off));
        c2 += bcf(__shfl_xor(bci(c2), off));
        c3 += bcf(__shfl_xor(bci(c3), off));
    }
    if (g == 0) {
        uint4 o;
        o.x = bci(c0); o.y = bci(c1); o.z = bci(c2); o.w = bci(c3);
        ((uint4*)q)[(size_t)wid * 16 + l] = o;
    }
}

// ---------------- pooling ----------------
__global__ __launch_bounds__(256) void pool_kernel(const f16_t* __restrict__ agg,
                                                   const int* __restrict__ batch,
                                                   float* __restrict__ pooled,
                                                   int* __restrict__ cntg, int N) {
    int wid = (blockIdx.x * 256 + threadIdx.x) >> 6;
    int lane = threadIdx.x & 63;
    int n0 = wid * 32;
    if (n0 >= N) return;
    int n1 = min(n0 + 32, N);
    const u32* au = (const u32*)agg;
    int gcur = batch[n0];
    float sx = 0.f, sy = 0.f;
    int cnt = 0;
    for (int n = n0; n < n1; ++n) {
        int g = batch[n];
        if (g != gcur) {
            atomicAdd(&pooled[gcur * 128 + lane * 2], sx);
            atomicAdd(&pooled[gcur * 128 + lane * 2 + 1], sy);
            if (lane == 0) atomicAdd(&cntg[gcur], cnt);
            gcur = g; sx = 0.f; sy = 0.f; cnt = 0;
        }
        u32 v = au[(size_t)n * 64 + lane];
        sx += f16lo(v);
        sy += f16hi(v);
        ++cnt;
    }
    atomicAdd(&pooled[gcur * 128 + lane * 2], sx);
    atomicAdd(&pooled[gcur * 128 + lane * 2 + 1], sy);
    if (lane == 0) atomicAdd(&cntg[gcur], cnt);
}

// ---------------- final ----------------
__global__ __launch_bounds__(256) void final_kernel(const float* __restrict__ pooled,
                                                    const int* __restrict__ cntg,
                                                    const float* __restrict__ out_w,
                                                    const float* __restrict__ out_b,
                                                    float* __restrict__ out, int total) {
    int idx = blockIdx.x * 256 + threadIdx.x;
    if (idx >= total) return;
    int g = idx >> 6, o = idx & 63;
    float c = fmaxf((float)cntg[g], 1.0f);
    float s = 0.f;
#pragma unroll 4
    for (int k = 0; k < 128; ++k) s += pooled[g * 128 + k] * out_w[k * 64 + o];
    out[idx] = s / c + out_b[o];
}

extern "C" void kernel_launch(void* const* d_in, const int* in_sizes, int n_in, void* d_out,
                              int out_size, void* d_ws, size_t ws_size, hipStream_t stream) {
    const float* x = (const float*)d_in[0];
    const int* ei = (const int*)d_in[1];
    const int* batch = (const int*)d_in[3];
    const float* cw[3][6];  // lin_w, lin_b, w1, b1, w2, b2
    for (int l = 0; l < 3; ++l)
        for (int j = 0; j < 6; ++j) cw[l][j] = (const float*)d_in[4 + l * 6 + j];
    const float* out_w = (const float*)d_in[22];
    const float* out_b = (const float*)d_in[23];
    float* out = (float*)d_out;

    const int N = in_sizes[0] / 128;
    const int E = in_sizes[1] / 2;
    const int G = out_size / 64;
    const int nbk = (N + 127) >> 7;       // buckets of 128 nodes (<=512 required)
    const int NB = 416;                   // edge-chunk blocks for hist/scat
    const int cap = E / nbk + 512;        // per-bucket capacity (mean + ~11 sigma)

    // ---- workspace layout ----
    char* base = (char*)d_ws;
    size_t off = 0;
    auto alloc = [&](size_t b) { size_t o = off; off += (b + 255) & ~(size_t)255; return o; };
    float* pooled = (float*)(base + alloc((size_t)G * 128 * 4));
    int* cntg = (int*)(base + alloc((size_t)G * 4));
    const size_t zero_bytes = off;
    int* hist = (int*)(base + alloc((size_t)NB * nbk * 4));
    int* bcnt = (int*)(base + alloc((size_t)nbk * 4));
    int* bsumB = (int*)(base + alloc((size_t)nbk * 4));
    int* bbase = (int*)(base + alloc((size_t)nbk * 4));
    int* row_ptr = (int*)(base + alloc((size_t)(N + 1) * 4));
    float* cntp1f = (float*)(base + alloc((size_t)N * 4));
    u16* colarr = (u16*)(base + alloc((size_t)E * 2));
    u32* bbuf = (u32*)(base + alloc((size_t)nbk * cap * 4));
    f16_t* xb = (f16_t*)(base + alloc((size_t)N * 128 * 2));  // layer input / agg output
    f16_t* q = (f16_t*)(base + alloc((size_t)N * 128 * 2));   // gather output
    f16_t* ab = (f16_t*)(base + alloc((size_t)N * 256 * 2));  // [a|b]
    f16_t* W12ct = (f16_t*)(base + alloc(3 * 32768 * 2));
    f16_t* W2t = (f16_t*)(base + alloc(3 * 16384 * 2));
    float* bias256c = (float*)(base + alloc(3 * 256 * 4));
    (void)ws_size; (void)n_in;

    hipMemsetAsync(d_ws, 0, zero_bytes, stream);

    // fused prep: convx | prepw x3 | histogram
    PrepArgs pa;
    pa.x = x; pa.xb = xb; pa.totalx = N * 128;
    pa.ei = ei; pa.E = E;
    pa.hist = hist; pa.nbk = nbk; pa.NB = NB;
    for (int l = 0; l < 3; ++l) {
        pa.lin_w[l] = cw[l][0]; pa.lin_b[l] = cw[l][1];
        pa.w1[l] = cw[l][2]; pa.b1[l] = cw[l][3]; pa.w2[l] = cw[l][4];
    }
    pa.W12ct = W12ct; pa.W2t = W2t; pa.bias256c = bias256c;
    const int nConvB = (N * 128 / 4 + 255) / 256;
    prep_kernel<<<nConvB + 3 * 193 + NB, 256, 0, stream>>>(pa, nConvB);

    // CSR: deterministic counting sort (no global atomics)
    hscan_kernel<<<nbk, 256, 0, stream>>>(hist, bcnt, nbk, NB);
    scat_kernel<<<NB, 256, 0, stream>>>(ei, hist, bbuf, E, NB, nbk, cap);
    part2_kernel<<<nbk, 128, 0, stream>>>(bbuf, bcnt, row_ptr, cntp1f, bsumB, cap, N);
    scanb_kernel<<<1, 512, 0, stream>>>(bsumB, bbase, row_ptr, nbk, N);
    part3_kernel<<<nbk, 128, 0, stream>>>(bbuf, bcnt, bbase, row_ptr, colarr, cap, N);

    const int gblocks = (N + 127) / 128;
    auto gemm = [&](const f16_t* X, const f16_t* Wt, const float* bias, const float* bias2,
                    const float* rowscale, f16_t* Y, int ncol, int relu_flag) {
        gemm_node<<<dim3(gblocks, ncol / 128), 256, 0, stream>>>(X, Wt, bias, bias2, rowscale, Y,
                                                                 N, ncol, relu_flag);
    };

    const f16_t* Xin = xb;
    for (int l = 0; l < 3; ++l) {
        gemm(Xin, W12ct + l * 32768, bias256c + l * 256, nullptr, nullptr, ab, 256, 0);
        gather_kernel<<<(N * 64 + 255) / 256, 256, 0, stream>>>(ab, row_ptr, colarr, q, N);
        gemm(q, W2t + l * 16384, nullptr, cw[l][5], cntp1f, xb, 128, 1);
        Xin = xb;
    }

    pool_kernel<<<((N + 31) / 32 * 64 + 255) / 256, 256, 0, stream>>>(Xin, batch, pooled, cntg, N);
    final_kernel<<<(G * 64 + 255) / 256, 256, 0, stream>>>(pooled, cntg, out_w, out_b, out,
                                                           G * 64);
}

// Round 11
// 475.416 us; speedup vs baseline: 1.6453x; 1.0517x over previous
//
#include <hip/hip_runtime.h>
#include <hip/hip_bf16.h>

// MPNN on MI355X.
// Identities: (1) (sum_e relu(a+b)) @ w2 pulls w2 out of the edge sum; (2) lin GEMM composed
// into w1 GEMM via W12c = lin_w@w1 (MFMA compose_kernel).
// b-half of the edge operand stored FP8 e4m3 (6.4MB working set) to cut gather random reads;
// a stays f16; accumulate f32.
// CSR build: deterministic counting sort (hist -> per-bucket scan -> rank scatter, LDS
// atomics only), colarr u16.
// R10 bug fixed: transpose LDS read-back loop covered only 1/4 of outputs (o=it*1024+tid with
// 256 threads); now 32 iterations of stride 256.

typedef _Float16 f16_t;
typedef f16_t f16x2 __attribute__((ext_vector_type(2)));
typedef f16_t f16x8 __attribute__((ext_vector_type(8)));
typedef float f32x4 __attribute__((ext_vector_type(4)));
typedef float f32x2v __attribute__((ext_vector_type(2)));
typedef unsigned int u32;
typedef unsigned short u16;
typedef unsigned char u8;

__device__ __forceinline__ float f16lo(u32 v) {
    return (float)__builtin_bit_cast(f16_t, (u16)(v & 0xffff));
}
__device__ __forceinline__ float f16hi(u32 v) {
    return (float)__builtin_bit_cast(f16_t, (u16)(v >> 16));
}
__device__ __forceinline__ u16 f16b(float x) { return __builtin_bit_cast(u16, (f16_t)x); }
__device__ __forceinline__ u32 f16pack(float x, float y) {
    return (u32)f16b(x) | ((u32)f16b(y) << 16);
}

// ---------------- fused prep: transposes | lin_w->f16 | bias | hist | convx ----------------
struct PrepArgs {
    const float* x; f16_t* xb; int totalx;
    const int* ei; int E;
    int* hist; int nbk; int NB;
    const float* lin_w[3]; const float* lin_b[3];
    const float* w1[3]; const float* b1[3]; const float* w2[3];
    f16_t* linw16;   // [3][128][128] f16 copy of lin_w
    f16_t* w1T;      // [3][256][128]: w1T[j][c] = w1sel(c,j)
    f16_t* W2t;      // [3][128][128]: W2t[j][k] = w2[k][j]
    float* bias256c; // [3][256]
};

__global__ __launch_bounds__(256) void prep_kernel(PrepArgs A, int nConvB) {
    __shared__ union { int hist[512]; u16 T16[128 * 130]; } shm;
    const int b = blockIdx.x, tid = threadIdx.x;
    const int nTr = 9, nLw = 48, nBias = 3;
    if (b < nTr) {
        // LDS-tiled 128x128 transpose -> f16. which: 0=w1 top, 1=w1 bottom, 2=w2
        int layer = b / 3, which = b % 3;
        const float* src; f16_t* dst;
        if (which == 0)      { src = A.w1[layer];          dst = A.w1T + layer * 32768; }
        else if (which == 1) { src = A.w1[layer] + 16384;  dst = A.w1T + layer * 32768 + 16384; }
        else                 { src = A.w2[layer];          dst = A.W2t + layer * 16384; }
#pragma unroll
        for (int it = 0; it < 16; ++it) {
            int idx = it * 1024 + tid * 4;     // coalesced float4 read
            int r = idx >> 7, c = idx & 127;
            float4 v = *(const float4*)(src + idx);
            *(u32*)&shm.T16[r * 130 + c] = f16pack(v.x, v.y);
            *(u32*)&shm.T16[r * 130 + c + 2] = f16pack(v.z, v.w);
        }
        __syncthreads();
#pragma unroll
        for (int it = 0; it < 32; ++it) {      // 32*256 = 8192 u32 outputs (FIX: was it*1024)
            int o = it * 256 + tid;            // u32 output index: j*64 + c2
            int j = o >> 6, c = (o & 63) * 2;
            u32 w = (u32)shm.T16[c * 130 + j] | ((u32)shm.T16[(c + 1) * 130 + j] << 16);
            ((u32*)dst)[o] = w;                // dst[j][c], coalesced
        }
        return;
    }
    if (b < nTr + nLw) {
        int i = (b - nTr) * 1024 + tid * 4;    // over 3*16384 f32
        int layer = i >> 14, off = i & 16383;
        float4 v = *(const float4*)(A.lin_w[layer] + off);
        *(uint2*)(A.linw16 + i) = make_uint2(f16pack(v.x, v.y), f16pack(v.z, v.w));
        return;
    }
    if (b < nTr + nLw + nBias) {
        int layer = b - nTr - nLw;
        int j = tid;  // 256 threads
        const float* w1p = A.w1[layer];
        const float* wcol = (j < 128) ? (w1p + j) : (w1p + 16384 + (j - 128));
        const float* lbp = A.lin_b[layer];
        float s = (j < 128) ? A.b1[layer][j] : 0.f;
        for (int c = 0; c < 128; ++c) s += lbp[c] * wcol[c * 128];  // coalesced across lanes
        A.bias256c[layer * 256 + j] = s;
        return;
    }
    if (b < nTr + nLw + nBias + A.NB) {
        // edge histogram: bucket = dst>>7, LDS counters only
        const int bb = b - nTr - nLw - nBias;
        const int nbk = A.nbk, E = A.E;
        for (int i = tid; i < nbk; i += 256) shm.hist[i] = 0;
        __syncthreads();
        const int chunk = (E + A.NB - 1) / A.NB;
        const int e0 = bb * chunk, e1 = min(E, e0 + chunk);
        for (int e = e0 + tid; e < e1; e += 256) atomicAdd(&shm.hist[A.ei[E + e] >> 7], 1);
        __syncthreads();
        for (int i = tid; i < nbk; i += 256) A.hist[(size_t)bb * nbk + i] = shm.hist[i];
        return;
    }
    // convx: fp32 -> f16
    int i = ((b - nTr - nLw - nBias - A.NB) * 256 + tid) * 4;
    if (i >= A.totalx) return;
    float4 v = *(const float4*)(A.x + i);
    *(uint2*)(A.xb + i) = make_uint2(f16pack(v.x, v.y), f16pack(v.z, v.w));
}

// ---------------- hscan: per-bucket exclusive scan of per-block counts ----------------
__global__ __launch_bounds__(256) void hscan_kernel(int* __restrict__ hist,
                                                    int* __restrict__ bcnt, int nbk, int NB) {
    __shared__ int sh[256];
    const int b = blockIdx.x, t = threadIdx.x;
    int run = 0;
    for (int c0 = 0; c0 < NB; c0 += 256) {
        int idx = c0 + t;
        int v = (idx < NB) ? hist[(size_t)idx * nbk + b] : 0;
        sh[t] = v;
        __syncthreads();
#pragma unroll
        for (int o = 1; o < 256; o <<= 1) {
            int u = (t >= o) ? sh[t - o] : 0;
            __syncthreads();
            sh[t] += u;
            __syncthreads();
        }
        if (idx < NB) hist[(size_t)idx * nbk + b] = run + sh[t] - v;
        int tot = sh[255];
        __syncthreads();
        run += tot;
    }
    if (t == 0) bcnt[b] = run;
}

// ---------------- scat: packed (dst&127)<<16|src at precomputed base + LDS rank ------------
__global__ __launch_bounds__(256) void scat_kernel(const int* __restrict__ ei,
                                                   const int* __restrict__ hist,
                                                   u32* __restrict__ bbuf, int E, int NB,
                                                   int nbk, int cap) {
    __shared__ int basep[512];
    __shared__ int cnt2[512];
    const int bb = blockIdx.x, t = threadIdx.x;
    for (int i = t; i < nbk; i += 256) {
        basep[i] = hist[(size_t)bb * nbk + i];
        cnt2[i] = 0;
    }
    __syncthreads();
    const int chunk = (E + NB - 1) / NB;
    const int e0 = bb * chunk, e1 = min(E, e0 + chunk);
    for (int e = e0 + t; e < e1; e += 256) {
        int dst = ei[E + e], src = ei[e];
        int bkt = dst >> 7;
        int r = atomicAdd(&cnt2[bkt], 1);  // LDS returning atomic: cheap
        int pp = basep[bkt] + r;
        if (pp < cap) bbuf[(size_t)bkt * cap + pp] = ((u32)(dst & 127) << 16) | (u32)src;
    }
}

// ---------------- part2: per-bucket degree + local scan ----------------
__global__ __launch_bounds__(128) void part2_kernel(const u32* __restrict__ bbuf,
                                                    const int* __restrict__ bcnt,
                                                    int* __restrict__ row_ptr,
                                                    float* __restrict__ cntp1f,
                                                    int* __restrict__ bsumB, int cap, int N) {
    __shared__ int ldeg[128];
    __shared__ int sh[128];
    const int b = blockIdx.x, t = threadIdx.x;
    ldeg[t] = 0;
    __syncthreads();
    const int cnt = min(bcnt[b], cap);
    const u32* p = bbuf + (size_t)b * cap;
    for (int i = t; i < cnt; i += 128) atomicAdd(&ldeg[p[i] >> 16], 1);
    __syncthreads();
    int d = ldeg[t];
    sh[t] = d;
    __syncthreads();
#pragma unroll
    for (int o = 1; o < 128; o <<= 1) {
        int u = (t >= o) ? sh[t - o] : 0;
        __syncthreads();
        sh[t] += u;
        __syncthreads();
    }
    int node = (b << 7) + t;
    if (node < N) {
        row_ptr[node] = sh[t] - d;
        cntp1f[node] = (float)(d + 1);
    }
    if (t == 127) bsumB[b] = sh[127];
}

// ---------------- scanB: exclusive scan of bucket totals (1 block) ----------------
__global__ __launch_bounds__(512) void scanb_kernel(const int* __restrict__ bsumB,
                                                    int* __restrict__ bbase,
                                                    int* __restrict__ row_ptr, int nbk, int N) {
    __shared__ int sh[512];
    const int t = threadIdx.x;
    int v = (t < nbk) ? bsumB[t] : 0;
    sh[t] = v;
    __syncthreads();
#pragma unroll
    for (int o = 1; o < 512; o <<= 1) {
        int u = (t >= o) ? sh[t - o] : 0;
        __syncthreads();
        sh[t] += u;
        __syncthreads();
    }
    if (t < nbk) bbase[t] = sh[t] - v;
    if (t == 511) row_ptr[N] = sh[511];
}

// ---------------- part3: finalize row_ptr, scatter u16 colarr ----------------
__global__ __launch_bounds__(128) void part3_kernel(const u32* __restrict__ bbuf,
                                                    const int* __restrict__ bcnt,
                                                    const int* __restrict__ bbase,
                                                    int* __restrict__ row_ptr,
                                                    u16* __restrict__ colarr, int cap, int N) {
    __shared__ int lcur[128];
    const int b = blockIdx.x, t = threadIdx.x;
    const int node = (b << 7) + t;
    const int bb = bbase[b];
    int rp = 0;
    if (node < N) {
        rp = row_ptr[node] + bb;
        row_ptr[node] = rp;
    }
    lcur[t] = rp;
    __syncthreads();
    const int cnt = min(bcnt[b], cap);
    const u32* p = bbuf + (size_t)b * cap;
    for (int i = t; i < cnt; i += 128) {
        u32 en = p[i];
        int addr = atomicAdd(&lcur[en >> 16], 1);
        colarr[addr] = (u16)(en & 0xffffu);
    }
}

// ---------------- shared MFMA tile: Y[128 rows x 128 cols] = X @ Wt^T ----------------
__device__ __forceinline__ void gemm_tile(const f16_t* __restrict__ X,
                                          const f16_t* __restrict__ Wt,
                                          const float* __restrict__ bias,
                                          const float* __restrict__ bias2,
                                          const float* __restrict__ rowscale,
                                          f16_t* __restrict__ Y, u8* __restrict__ Y8, int N,
                                          int ldc, int relu_flag, int row0, int coloff) {
    __shared__ f16_t sX[128 * 128];
    __shared__ f16_t sW[128 * 128];
    const int tid = threadIdx.x;
#pragma unroll
    for (int it = 0; it < 8; ++it) {
        int idx = tid + it * 256;
        int r = idx >> 4, c8 = idx & 15;
        int gr = row0 + r;
        uint4 v = make_uint4(0, 0, 0, 0);
        if (gr < N) v = *(const uint4*)(X + (size_t)gr * 128 + c8 * 8);
        *(uint4*)(&sX[r * 128 + (c8 ^ (r & 7)) * 8]) = v;
    }
#pragma unroll
    for (int it = 0; it < 8; ++it) {
        int idx = tid + it * 256;
        int r = idx >> 4, c8 = idx & 15;
        uint4 v = *(const uint4*)(Wt + (size_t)(coloff + r) * 128 + c8 * 8);
        *(uint4*)(&sW[r * 128 + (c8 ^ (r & 7)) * 8]) = v;
    }
    __syncthreads();
    const int wave = tid >> 6, lane = tid & 63;
    const int m = lane & 15, q = lane >> 4;
    const int sw = m & 7;
    f32x4 acc[2][8];
#pragma unroll
    for (int rt = 0; rt < 2; ++rt)
#pragma unroll
        for (int t = 0; t < 8; ++t) acc[rt][t] = (f32x4){0.f, 0.f, 0.f, 0.f};
#pragma unroll
    for (int kk = 0; kk < 4; ++kk) {
        const int g = (kk * 4 + q) ^ sw;
        f16x8 a0 = *(const f16x8*)(&sX[(wave * 32 + m) * 128 + g * 8]);
        f16x8 a1 = *(const f16x8*)(&sX[(wave * 32 + 16 + m) * 128 + g * 8]);
#pragma unroll
        for (int t = 0; t < 8; ++t) {
            f16x8 bfr = *(const f16x8*)(&sW[(t * 16 + m) * 128 + g * 8]);
            acc[0][t] = __builtin_amdgcn_mfma_f32_16x16x32_f16(a0, bfr, acc[0][t], 0, 0, 0);
            acc[1][t] = __builtin_amdgcn_mfma_f32_16x16x32_f16(a1, bfr, acc[1][t], 0, 0, 0);
        }
    }
#pragma unroll
    for (int t = 0; t < 8; ++t) {
        int col = coloff + t * 16 + m;
        float bv = bias ? bias[col] : 0.f;
        float b2v = bias2 ? bias2[col] : 0.f;
#pragma unroll
        for (int rt = 0; rt < 2; ++rt) {
#pragma unroll
            for (int j = 0; j < 4; ++j) {
                int r = row0 + wave * 32 + rt * 16 + q * 4 + j;
                if (r < N) {
                    float v = acc[rt][t][j] + bv;
                    if (rowscale) v += rowscale[r] * b2v;
                    if (relu_flag) v = fmaxf(v, 0.f);
                    if (Y8 && coloff == 128) {
                        u32 w = __builtin_amdgcn_cvt_pk_fp8_f32(v, v, 0, false);
                        Y8[(size_t)r * 128 + (col - 128)] = (u8)w;  // fp8 e4m3
                    } else {
                        Y[(size_t)r * ldc + col] = (f16_t)v;
                    }
                }
            }
        }
    }
}

__global__ __launch_bounds__(256) void gemm_node(const f16_t* __restrict__ X,
                                                 const f16_t* __restrict__ Wt,
                                                 const float* __restrict__ bias,
                                                 const float* __restrict__ bias2,
                                                 const float* __restrict__ rowscale,
                                                 f16_t* __restrict__ Y, u8* __restrict__ Y8,
                                                 int N, int ldc, int relu_flag) {
    gemm_tile(X, Wt, bias, bias2, rowscale, Y, Y8, N, ldc, relu_flag, blockIdx.x * 128,
              blockIdx.y * 128);
}

// compose: W12ct[layer][j][k] = sum_c w1T[layer][j][c] * linw16[layer][k][c]  (MFMA)
__global__ __launch_bounds__(256) void compose_kernel(const f16_t* __restrict__ w1T,
                                                      const f16_t* __restrict__ linw16,
                                                      f16_t* __restrict__ W12ct) {
    int layer = blockIdx.x >> 1, rb = blockIdx.x & 1;
    gemm_tile(w1T + layer * 32768, linw16 + layer * 16384, nullptr, nullptr, nullptr,
              W12ct + layer * 32768, nullptr, 256, 128, 0, rb * 128, 0);
}

// ---------------- gather: a f16, b fp8, accumulate f32; 16 edges in flight ----------------
__global__ __launch_bounds__(256) void gather_kernel(const f16_t* __restrict__ aArr,
                                                     const u8* __restrict__ b8,
                                                     const int* __restrict__ row_ptr,
                                                     const u16* __restrict__ colarr,
                                                     f16_t* __restrict__ q, int N) {
    int wid = (blockIdx.x * 256 + threadIdx.x) >> 6;
    int lane = threadIdx.x & 63;
    if (wid >= N) return;
    const int g = lane >> 4, l = lane & 15;
    uint4 A = ((const uint4*)aArr)[(size_t)wid * 16 + l];
    float a0 = f16lo(A.x), a1 = f16hi(A.x), a2 = f16lo(A.y), a3 = f16hi(A.y);
    float a4 = f16lo(A.z), a5 = f16hi(A.z), a6 = f16lo(A.w), a7 = f16hi(A.w);
    float c0 = 0.f, c1 = 0.f, c2 = 0.f, c3 = 0.f, c4 = 0.f, c5 = 0.f, c6 = 0.f, c7 = 0.f;
    const uint2* b8u = (const uint2*)b8;  // row = 16 uint2
    auto accum = [&](uint2 B) {
        f32x2v p0 = __builtin_amdgcn_cvt_pk_f32_fp8(B.x, false);
        f32x2v p1 = __builtin_amdgcn_cvt_pk_f32_fp8(B.x, true);
        f32x2v p2 = __builtin_amdgcn_cvt_pk_f32_fp8(B.y, false);
        f32x2v p3 = __builtin_amdgcn_cvt_pk_f32_fp8(B.y, true);
        c0 += fmaxf(a0 + p0.x, 0.f); c1 += fmaxf(a1 + p0.y, 0.f);
        c2 += fmaxf(a2 + p1.x, 0.f); c3 += fmaxf(a3 + p1.y, 0.f);
        c4 += fmaxf(a4 + p2.x, 0.f); c5 += fmaxf(a5 + p2.y, 0.f);
        c6 += fmaxf(a6 + p3.x, 0.f); c7 += fmaxf(a7 + p3.y, 0.f);
    };
    if (g == 0) accum(b8u[(size_t)wid * 16 + l]);  // self loop
    int e0 = row_ptr[wid], e1 = row_ptr[wid + 1];
    int e = e0;
    for (; e + 16 <= e1; e += 16) {
        int s0 = colarr[e + g], s1 = colarr[e + 4 + g];
        int s2 = colarr[e + 8 + g], s3 = colarr[e + 12 + g];
        uint2 B0 = b8u[(size_t)s0 * 16 + l];
        uint2 B1 = b8u[(size_t)s1 * 16 + l];
        uint2 B2 = b8u[(size_t)s2 * 16 + l];
        uint2 B3 = b8u[(size_t)s3 * 16 + l];
        accum(B0); accum(B1); accum(B2); accum(B3);
    }
    for (; e < e1; e += 4) {
        int i0 = e + g;
        if (i0 < e1) accum(b8u[(size_t)colarr[i0] * 16 + l]);
    }
#pragma unroll
    for (int off = 16; off < 64; off <<= 1) {
        c0 += __shfl_xor(c0, off); c1 += __shfl_xor(c1, off);
        c2 += __shfl_xor(c2, off); c3 += __shfl_xor(c3, off);
        c4 += __shfl_xor(c4, off); c5 += __shfl_xor(c5, off);
        c6 += __shfl_xor(c6, off); c7 += __shfl_xor(c7, off);
    }
    if (g == 0) {
        uint4 o;
        o.x = f16pack(c0, c1); o.y = f16pack(c2, c3);
        o.z = f16pack(c4, c5); o.w = f16pack(c6, c7);
        ((uint4*)q)[(size_t)wid * 16 + l] = o;
    }
}

// ---------------- pooling ----------------
__global__ __launch_bounds__(256) void pool_kernel(const f16_t* __restrict__ agg,
                                                   const int* __restrict__ batch,
                                                   float* __restrict__ pooled,
                                                   int* __restrict__ cntg, int N) {
    int wid = (blockIdx.x * 256 + threadIdx.x) >> 6;
    int lane = threadIdx.x & 63;
    int n0 = wid * 32;
    if (n0 >= N) return;
    int n1 = min(n0 + 32, N);
    const u32* au = (const u32*)agg;
    int gcur = batch[n0];
    float sx = 0.f, sy = 0.f;
    int cnt = 0;
    for (int n = n0; n < n1; ++n) {
        int g = batch[n];
        if (g != gcur) {
            atomicAdd(&pooled[gcur * 128 + lane * 2], sx);
            atomicAdd(&pooled[gcur * 128 + lane * 2 + 1], sy);
            if (lane == 0) atomicAdd(&cntg[gcur], cnt);
            gcur = g; sx = 0.f; sy = 0.f; cnt = 0;
        }
        u32 v = au[(size_t)n * 64 + lane];
        sx += f16lo(v);
        sy += f16hi(v);
        ++cnt;
    }
    atomicAdd(&pooled[gcur * 128 + lane * 2], sx);
    atomicAdd(&pooled[gcur * 128 + lane * 2 + 1], sy);
    if (lane == 0) atomicAdd(&cntg[gcur], cnt);
}

// ---------------- final ----------------
__global__ __launch_bounds__(256) void final_kernel(const float* __restrict__ pooled,
                                                    const int* __restrict__ cntg,
                                                    const float* __restrict__ out_w,
                                                    const float* __restrict__ out_b,
                                                    float* __restrict__ out, int total) {
    int idx = blockIdx.x * 256 + threadIdx.x;
    if (idx >= total) return;
    int g = idx >> 6, o = idx & 63;
    float c = fmaxf((float)cntg[g], 1.0f);
    float s = 0.f;
#pragma unroll 4
    for (int k = 0; k < 128; ++k) s += pooled[g * 128 + k] * out_w[k * 64 + o];
    out[idx] = s / c + out_b[o];
}

extern "C" void kernel_launch(void* const* d_in, const int* in_sizes, int n_in, void* d_out,
                              int out_size, void* d_ws, size_t ws_size, hipStream_t stream) {
    const float* x = (const float*)d_in[0];
    const int* ei = (const int*)d_in[1];
    const int* batch = (const int*)d_in[3];
    const float* cw[3][6];  // lin_w, lin_b, w1, b1, w2, b2
    for (int l = 0; l < 3; ++l)
        for (int j = 0; j < 6; ++j) cw[l][j] = (const float*)d_in[4 + l * 6 + j];
    const float* out_w = (const float*)d_in[22];
    const float* out_b = (const float*)d_in[23];
    float* out = (float*)d_out;

    const int N = in_sizes[0] / 128;
    const int E = in_sizes[1] / 2;
    const int G = out_size / 64;
    const int nbk = (N + 127) >> 7;
    const int NB = 416;
    const int cap = E / nbk + 512;

    // ---- workspace layout ----
    char* base = (char*)d_ws;
    size_t off = 0;
    auto alloc = [&](size_t b) { size_t o = off; off += (b + 255) & ~(size_t)255; return o; };
    float* pooled = (float*)(base + alloc((size_t)G * 128 * 4));
    int* cntg = (int*)(base + alloc((size_t)G * 4));
    const size_t zero_bytes = off;
    int* hist = (int*)(base + alloc((size_t)NB * nbk * 4));
    int* bcnt = (int*)(base + alloc((size_t)nbk * 4));
    int* bsumB = (int*)(base + alloc((size_t)nbk * 4));
    int* bbase = (int*)(base + alloc((size_t)nbk * 4));
    int* row_ptr = (int*)(base + alloc((size_t)(N + 1) * 4));
    float* cntp1f = (float*)(base + alloc((size_t)N * 4));
    u16* colarr = (u16*)(base + alloc((size_t)E * 2));
    u32* bbuf = (u32*)(base + alloc((size_t)nbk * cap * 4));
    f16_t* xb = (f16_t*)(base + alloc((size_t)N * 128 * 2));   // layer input / agg output
    f16_t* q = (f16_t*)(base + alloc((size_t)N * 128 * 2));    // gather output
    f16_t* aArr = (f16_t*)(base + alloc((size_t)N * 128 * 2)); // a-half of edge operand
    u8* b8 = (u8*)(base + alloc((size_t)N * 128));             // b-half, fp8 e4m3
    f16_t* linw16 = (f16_t*)(base + alloc(3 * 16384 * 2));
    f16_t* w1T = (f16_t*)(base + alloc(3 * 32768 * 2));
    f16_t* W12ct = (f16_t*)(base + alloc(3 * 32768 * 2));
    f16_t* W2t = (f16_t*)(base + alloc(3 * 16384 * 2));
    float* bias256c = (float*)(base + alloc(3 * 256 * 4));
    (void)ws_size; (void)n_in;

    hipMemsetAsync(d_ws, 0, zero_bytes, stream);

    // fused prep
    PrepArgs pa;
    pa.x = x; pa.xb = xb; pa.totalx = N * 128;
    pa.ei = ei; pa.E = E;
    pa.hist = hist; pa.nbk = nbk; pa.NB = NB;
    for (int l = 0; l < 3; ++l) {
        pa.lin_w[l] = cw[l][0]; pa.lin_b[l] = cw[l][1];
        pa.w1[l] = cw[l][2]; pa.b1[l] = cw[l][3]; pa.w2[l] = cw[l][4];
    }
    pa.linw16 = linw16; pa.w1T = w1T; pa.W2t = W2t; pa.bias256c = bias256c;
    const int nConvB = (N * 128 / 4 + 255) / 256;
    prep_kernel<<<9 + 48 + 3 + NB + nConvB, 256, 0, stream>>>(pa, nConvB);

    // compose W12c with MFMA (6 blocks)
    compose_kernel<<<6, 256, 0, stream>>>(w1T, linw16, W12ct);

    // CSR: deterministic counting sort
    hscan_kernel<<<nbk, 256, 0, stream>>>(hist, bcnt, nbk, NB);
    scat_kernel<<<NB, 256, 0, stream>>>(ei, hist, bbuf, E, NB, nbk, cap);
    part2_kernel<<<nbk, 128, 0, stream>>>(bbuf, bcnt, row_ptr, cntp1f, bsumB, cap, N);
    scanb_kernel<<<1, 512, 0, stream>>>(bsumB, bbase, row_ptr, nbk, N);
    part3_kernel<<<nbk, 128, 0, stream>>>(bbuf, bcnt, bbase, row_ptr, colarr, cap, N);

    const int gblocks = (N + 127) / 128;
    const f16_t* Xin = xb;
    for (int l = 0; l < 3; ++l) {
        // [a | b8] = Xin @ W12c + bias; a f16, b fp8 (bias applied pre-round)
        gemm_node<<<dim3(gblocks, 2), 256, 0, stream>>>(Xin, W12ct + l * 32768,
                                                        bias256c + l * 256, nullptr, nullptr,
                                                        aArr, b8, N, 128, 0);
        gather_kernel<<<(N * 64 + 255) / 256, 256, 0, stream>>>(aArr, b8, row_ptr, colarr, q, N);
        // xb = relu(q @ w2 + (deg+1)*b2)
        gemm_node<<<dim3(gblocks, 1), 256, 0, stream>>>(q, W2t + l * 16384, nullptr, cw[l][5],
                                                        cntp1f, xb, nullptr, N, 128, 1);
        Xin = xb;
    }

    pool_kernel<<<((N + 31) / 32 * 64 + 255) / 256, 256, 0, stream>>>(Xin, batch, pooled, cntg, N);
    final_kernel<<<(G * 64 + 255) / 256, 256, 0, stream>>>(pooled, cntg, out_w, out_b, out,
                                                           G * 64);
}